// Round 1
// baseline (1709.968 us; speedup 1.0000x reference)
//
#include <hip/hip_runtime.h>
#include <math.h>

#define NB 65536
#define NQ 15
#define ND 128
#define NCH 256
#define NE 15
#define TS 64

// ---------------- init: zero the per-expert counters ----------------
__global__ __launch_bounds__(64) void k_init(int* counts) {
  int t = threadIdx.x;
  if (t < 16) counts[t] = 0;
}

// ---------------- phase 1: scores, logits, argmax/expert-id ----------------
// one wave per sample; lanes 0-31 handle even rows, 32-63 odd rows (float4/lane)
__global__ __launch_bounds__(256) void k_scene(
    const float* __restrict__ ld, const float* __restrict__ sW,
    const float* __restrict__ sb, float* __restrict__ logits,
    unsigned char* __restrict__ eid, int* __restrict__ counts)
{
  __shared__ float dots[4][16];
  const int tid = threadIdx.x;
  const int w = tid >> 6, lane = tid & 63;
  const int b = (blockIdx.x << 2) + w;
  const int col = (lane & 31) << 2;
  const int half = lane >> 5;
  const float4 w4 = *(const float4*)(sW + col);
  const float* base = ld + (size_t)b * (NQ * ND);
  #pragma unroll
  for (int i = 0; i < 8; ++i) {
    int q = 2 * i + half;                // 0..15; 15 is invalid
    float4 x = make_float4(0.f, 0.f, 0.f, 0.f);
    if (q < 15) x = *(const float4*)(base + q * ND + col);
    float d = x.x * w4.x + x.y * w4.y + x.z * w4.z + x.w * w4.w;
    d += __shfl_xor(d, 16);
    d += __shfl_xor(d, 8);
    d += __shfl_xor(d, 4);
    d += __shfl_xor(d, 2);
    d += __shfl_xor(d, 1);
    if ((lane & 31) == 0 && q < 15) dots[w][q] = d;
  }
  __syncthreads();
  const int idx = lane & 15;
  float raw = dots[w][idx & 15];         // idx==15 slot unwritten -> masked below
  float v = (idx < 15) ? raw : -3.402823466e38f;
  if (lane < 15) logits[(size_t)b * 15 + lane] = raw + sb[0];
  int ai = idx;
  #pragma unroll
  for (int m = 1; m <= 8; m <<= 1) {     // argmax over 16-lane group, first-occurrence ties
    float v2 = __shfl_xor(v, m);
    int  i2 = __shfl_xor(ai, m);
    if (v2 > v || (v2 == v && i2 < ai)) { v = v2; ai = i2; }
  }
  if (lane == 0) {
    eid[b] = (unsigned char)ai;
    atomicAdd(&counts[ai], 1);
  }
}

// ---------------- tiny scan: offsets, cursors, tile bases ----------------
__global__ void k_scan(const int* __restrict__ counts, int* __restrict__ offsets,
                       int* __restrict__ cursor, int* __restrict__ tb) {
  if (threadIdx.x == 0 && blockIdx.x == 0) {
    int o = 0, t = 0;
    offsets[0] = 0; tb[0] = 0;
    for (int e = 0; e < NE; ++e) {
      cursor[e] = o;
      o += counts[e]; offsets[e + 1] = o;
      t += (counts[e] + TS - 1) / TS; tb[e + 1] = t;
    }
  }
}

// ---------------- scatter: build per-expert sample lists (wave-aggregated atomics) ---------
__global__ __launch_bounds__(256) void k_scatter(const unsigned char* __restrict__ eid,
                                                 int* __restrict__ cursor, int* __restrict__ perm)
{
  int b = blockIdx.x * 256 + threadIdx.x;
  int e = eid[b];
  unsigned long long lt = (1ull << (threadIdx.x & 63)) - 1ull;
  #pragma unroll 1
  for (int ee = 0; ee < NE; ++ee) {
    unsigned long long m = __ballot(e == ee);
    if (e == ee) {
      int off = __popcll(m & lt);
      int base = 0;
      if (off == 0) base = atomicAdd(&cursor[ee], __popcll(m));
      int leader = __ffsll(m) - 1;
      base = __shfl(base, leader);
      perm[base + off] = b;
    }
  }
}

// ---------------- phase 2: grouped per-expert MLP, 64-sample tiles ----------------
// LDS: GT[128][64] (32K, aliased by BT2[64][128]) + Bc[32][256] (32K) + H[64][260] (65K) + rowB
__global__ __launch_bounds__(256) void k_mlp(
  const float* __restrict__ ld, const float* __restrict__ W1, const float* __restrict__ b1,
  const float* __restrict__ W2, const float* __restrict__ b2,
  const int* __restrict__ offsets, const int* __restrict__ tb,
  const int* __restrict__ perm, float* __restrict__ outv)
{
  __shared__ __align__(16) char smem[132352];
  float (*GT)[64]   = (float (*)[64])(smem);            // [128 k][64 row]
  float (*Bc)[256]  = (float (*)[256])(smem + 32768);   // [32 k][256 ch]
  float (*Hs)[260]  = (float (*)[260])(smem + 65536);   // [64 row][256 ch] (+4 pad)
  float (*BT2)[128] = (float (*)[128])(smem);           // [64 k][128 d] aliases GT
  int* rowB = (int*)(smem + 132096);

  const int bi = blockIdx.x;
  int e = 0;
  while (e < NE && tb[e + 1] <= bi) ++e;
  if (e >= NE) return;
  const int t = bi - tb[e];
  const int start = offsets[e] + t * TS;
  const int n = min(TS, offsets[e + 1] - start);
  const int tid = threadIdx.x;

  if (tid < TS) {
    int bb = -1;
    if (tid < n) bb = perm[start + tid];
    rowB[tid] = bb;
  }
  __syncthreads();

  // stage gathered G rows transposed: GT[k][row]; lane-per-row -> conflict-free LDS writes
  #pragma unroll
  for (int it = 0; it < 8; ++it) {
    int idx = it * 256 + tid;
    int k4 = idx >> 6, row = idx & 63;
    int bb = rowB[row];
    float4 x = make_float4(0.f, 0.f, 0.f, 0.f);
    if (bb >= 0) x = *(const float4*)(ld + (size_t)bb * (NQ * ND) + e * ND + (k4 << 2));
    GT[k4 * 4 + 0][row] = x.x;
    GT[k4 * 4 + 1][row] = x.y;
    GT[k4 * 4 + 2][row] = x.z;
    GT[k4 * 4 + 3][row] = x.w;
  }

  const float* W1e = W1 + (size_t)e * NCH * ND;
  const float* W2e = W2 + (size_t)e * ND * NCH;

  // ---- layer 1: H[64][256] = G @ W1^T ; 8x8 micro-tile per thread
  const int cx = tid & 31, ry = tid >> 5;
  float acc[8][8];
  #pragma unroll
  for (int r = 0; r < 8; ++r)
    #pragma unroll
    for (int c = 0; c < 8; ++c) acc[r][c] = 0.f;

  for (int kc = 0; kc < 4; ++kc) {
    __syncthreads();                       // GT staged / previous Bc consumed
    {
      const float* wrow = W1e + (size_t)tid * ND + kc * 32;
      #pragma unroll
      for (int j4 = 0; j4 < 8; ++j4) {
        float4 x = *(const float4*)(wrow + (j4 << 2));
        Bc[j4 * 4 + 0][tid] = x.x; Bc[j4 * 4 + 1][tid] = x.y;
        Bc[j4 * 4 + 2][tid] = x.z; Bc[j4 * 4 + 3][tid] = x.w;
      }
    }
    __syncthreads();
    for (int kk = 0; kk < 32; ++kk) {
      int k = kc * 32 + kk;
      float a[8], bv[8];
      *(float4*)&a[0] = *(const float4*)&GT[k][ry * 8];
      *(float4*)&a[4] = *(const float4*)&GT[k][ry * 8 + 4];
      *(float4*)&bv[0] = *(const float4*)&Bc[kk][cx * 8];
      *(float4*)&bv[4] = *(const float4*)&Bc[kk][cx * 8 + 4];
      #pragma unroll
      for (int r = 0; r < 8; ++r)
        #pragma unroll
        for (int c = 0; c < 8; ++c)
          acc[r][c] = fmaf(a[r], bv[c], acc[r][c]);
    }
  }

  // bias + exact gelu -> H (row-major, float4 stores)
  float bias1[8];
  *(float4*)&bias1[0] = *(const float4*)(b1 + e * NCH + cx * 8);
  *(float4*)&bias1[4] = *(const float4*)(b1 + e * NCH + cx * 8 + 4);
  #pragma unroll
  for (int r = 0; r < 8; ++r) {
    float hv[8];
    #pragma unroll
    for (int c = 0; c < 8; ++c) {
      float x = acc[r][c] + bias1[c];
      hv[c] = 0.5f * x * (1.f + erff(x * 0.70710678118654752f));
    }
    *(float4*)&Hs[ry * 8 + r][cx * 8]     = *(float4*)&hv[0];
    *(float4*)&Hs[ry * 8 + r][cx * 8 + 4] = *(float4*)&hv[4];
  }

  // ---- layer 2: Out[64][128] = H @ W2^T ; 4x8 micro-tile per thread
  const int cg = tid & 15, rg = tid >> 4;
  float acc2[4][8];
  #pragma unroll
  for (int r = 0; r < 4; ++r)
    #pragma unroll
    for (int c = 0; c < 8; ++c) acc2[r][c] = 0.f;

  for (int kc = 0; kc < 4; ++kc) {
    __syncthreads();                       // all GT readers done (alias) / H written / prev BT2 consumed
    #pragma unroll
    for (int it = 0; it < 8; ++it) {
      int idx = it * 256 + tid;
      int d = idx & 127, kk4 = idx >> 7;   // 0..15
      float4 x = *(const float4*)(W2e + (size_t)d * NCH + kc * 64 + (kk4 << 2));
      BT2[kk4 * 4 + 0][d] = x.x; BT2[kk4 * 4 + 1][d] = x.y;
      BT2[kk4 * 4 + 2][d] = x.z; BT2[kk4 * 4 + 3][d] = x.w;
    }
    __syncthreads();
    for (int kk = 0; kk < 64; ++kk) {
      int k = kc * 64 + kk;
      float a[4], bv[8];
      #pragma unroll
      for (int i = 0; i < 4; ++i) a[i] = Hs[rg * 4 + i][k];
      *(float4*)&bv[0] = *(const float4*)&BT2[kk][cg * 8];
      *(float4*)&bv[4] = *(const float4*)&BT2[kk][cg * 8 + 4];
      #pragma unroll
      for (int r = 0; r < 4; ++r)
        #pragma unroll
        for (int c = 0; c < 8; ++c)
          acc2[r][c] = fmaf(a[r], bv[c], acc2[r][c]);
    }
  }

  float bias2[8];
  *(float4*)&bias2[0] = *(const float4*)(b2 + e * ND + cg * 8);
  *(float4*)&bias2[4] = *(const float4*)(b2 + e * ND + cg * 8 + 4);
  #pragma unroll
  for (int r = 0; r < 4; ++r) {
    int row = rg * 4 + r;
    int bb = rowB[row];
    if (bb < 0) continue;
    float ov[8];
    #pragma unroll
    for (int c = 0; c < 8; ++c) ov[c] = acc2[r][c] + bias2[c];
    *(float4*)(outv + (size_t)bb * ND + cg * 8)     = *(float4*)&ov[0];
    *(float4*)(outv + (size_t)bb * ND + cg * 8 + 4) = *(float4*)&ov[4];
  }
}

extern "C" void kernel_launch(void* const* d_in, const int* in_sizes, int n_in,
                              void* d_out, int out_size, void* d_ws, size_t ws_size,
                              hipStream_t stream) {
  const float* ld = (const float*)d_in[0];
  const float* sW = (const float*)d_in[1];
  const float* sb = (const float*)d_in[2];
  const float* W1 = (const float*)d_in[3];
  const float* b1 = (const float*)d_in[4];
  const float* W2 = (const float*)d_in[5];
  const float* b2 = (const float*)d_in[6];
  float* outv = (float*)d_out;                 // [B,128]
  float* logits = outv + (size_t)NB * ND;      // [B,15]

  int* counts  = (int*)d_ws;                   // 16
  int* offsets = counts + 16;                  // 17
  int* cursor  = counts + 33;                  // 16
  int* tb      = counts + 49;                  // 17
  unsigned char* eid = (unsigned char*)(counts + 80);      // byte 320, len 65536
  int* perm = (int*)((char*)d_ws + 320 + 65536);           // byte 65856, len B

  k_init<<<1, 64, 0, stream>>>(counts);
  k_scene<<<NB / 4, 256, 0, stream>>>(ld, sW, sb, logits, eid, counts);
  k_scan<<<1, 64, 0, stream>>>(counts, offsets, cursor, tb);
  k_scatter<<<NB / 256, 256, 0, stream>>>(eid, cursor, perm);
  k_mlp<<<NB / TS + NE, 256, 0, stream>>>(ld, W1, b1, W2, b2, offsets, tb, perm, outv);
}

// Round 2
// 925.358 us; speedup vs baseline: 1.8479x; 1.8479x over previous
//
#include <hip/hip_runtime.h>
#include <math.h>

#define NB 65536
#define NQ 15
#define ND 128
#define NCH 256
#define NE 15
#define TS 64

// ---------------- init: zero padded per-expert counters ----------------
__global__ __launch_bounds__(512) void k_init(int* counts) {
  counts[threadIdx.x] = 0;   // zeros counts[512]
}

// ---------------- phase 1: scores, logits, expert-id (NO atomics) ----------------
__global__ __launch_bounds__(256) void k_scene(
    const float* __restrict__ ld, const float* __restrict__ sW,
    const float* __restrict__ sb, float* __restrict__ logits,
    unsigned char* __restrict__ eid)
{
  __shared__ float dots[4][16];
  const int tid = threadIdx.x;
  const int w = tid >> 6, lane = tid & 63;
  const int b = (blockIdx.x << 2) + w;
  const int col = (lane & 31) << 2;
  const int half = lane >> 5;
  const float4 w4 = *(const float4*)(sW + col);
  const float* base = ld + (size_t)b * (NQ * ND);
  #pragma unroll
  for (int i = 0; i < 8; ++i) {
    int q = 2 * i + half;                // 0..15; 15 invalid
    float4 x = make_float4(0.f, 0.f, 0.f, 0.f);
    if (q < 15) x = *(const float4*)(base + q * ND + col);
    float d = x.x * w4.x + x.y * w4.y + x.z * w4.z + x.w * w4.w;
    d += __shfl_xor(d, 16);
    d += __shfl_xor(d, 8);
    d += __shfl_xor(d, 4);
    d += __shfl_xor(d, 2);
    d += __shfl_xor(d, 1);
    if ((lane & 31) == 0 && q < 15) dots[w][q] = d;
  }
  __syncthreads();
  const int idx = lane & 15;
  float raw = dots[w][idx & 15];
  float v = (idx < 15) ? raw : -3.402823466e38f;
  if (lane < 15) logits[(size_t)b * 15 + lane] = raw + sb[0];
  int ai = idx;
  #pragma unroll
  for (int m = 1; m <= 8; m <<= 1) {
    float v2 = __shfl_xor(v, m);
    int  i2 = __shfl_xor(ai, m);
    if (v2 > v || (v2 == v && i2 < ai)) { v = v2; ai = i2; }
  }
  if (lane == 0) eid[b] = (unsigned char)ai;
}

// ---------------- histogram: LDS sub-hists -> padded global atomics ----------------
__global__ __launch_bounds__(256) void k_hist(const unsigned char* __restrict__ eid,
                                              int* __restrict__ counts)
{
  __shared__ int h[4][16];
  const int tid = threadIdx.x, w = tid >> 6;
  if ((tid & 63) < 16) h[w][tid & 63] = 0;
  __syncthreads();
  uchar4 e4 = ((const uchar4*)eid)[blockIdx.x * 256 + tid];
  atomicAdd(&h[w][e4.x], 1);
  atomicAdd(&h[w][e4.y], 1);
  atomicAdd(&h[w][e4.z], 1);
  atomicAdd(&h[w][e4.w], 1);
  __syncthreads();
  if (tid < 15) {
    int t = h[0][tid] + h[1][tid] + h[2][tid] + h[3][tid];
    atomicAdd(&counts[tid * 32], t);          // each counter on its own 128B line
  }
}

// ---------------- tiny scan ----------------
__global__ void k_scan(const int* __restrict__ counts, int* __restrict__ offsets,
                       int* __restrict__ cursor, int* __restrict__ tb) {
  if (threadIdx.x == 0 && blockIdx.x == 0) {
    int o = 0, t = 0;
    offsets[0] = 0; tb[0] = 0;
    for (int e = 0; e < NE; ++e) {
      cursor[e * 32] = o;
      o += counts[e * 32]; offsets[e + 1] = o;
      t += (counts[e * 32] + TS - 1) / TS; tb[e + 1] = t;
    }
  }
}

// ---------------- scatter: wave-aggregated atomics, padded cursors ----------------
__global__ __launch_bounds__(256) void k_scatter(const unsigned char* __restrict__ eid,
                                                 int* __restrict__ cursor, int* __restrict__ perm)
{
  int b = blockIdx.x * 256 + threadIdx.x;
  int e = eid[b];
  unsigned long long lt = (1ull << (threadIdx.x & 63)) - 1ull;
  #pragma unroll 1
  for (int ee = 0; ee < NE; ++ee) {
    unsigned long long m = __ballot(e == ee);
    if (e == ee) {
      int off = __popcll(m & lt);
      int base = 0;
      if (off == 0) base = atomicAdd(&cursor[ee * 32], __popcll(m));
      int leader = __ffsll(m) - 1;
      base = __shfl(base, leader);
      perm[base + off] = b;
    }
  }
}

// ---------------- phase 2: grouped per-expert MLP, 64-sample tiles, 512 thr ----------------
__global__ __launch_bounds__(512) void k_mlp(
  const float* __restrict__ ld, const float* __restrict__ W1, const float* __restrict__ b1,
  const float* __restrict__ W2, const float* __restrict__ b2,
  const int* __restrict__ offsets, const int* __restrict__ tb,
  const int* __restrict__ perm, float* __restrict__ outv)
{
  __shared__ __align__(16) char smem[132352];
  float (*GT)[64]   = (float (*)[64])(smem);            // [128 k][64 row]
  float (*Bc)[256]  = (float (*)[256])(smem + 32768);   // [32 k][256 ch]
  float (*Hs)[260]  = (float (*)[260])(smem + 65536);   // [64 row][260]
  float (*BT2)[128] = (float (*)[128])(smem);           // [64 k][128 d] aliases GT
  int* rowB = (int*)(smem + 132096);

  const int bi = blockIdx.x;
  int e = 0;
  while (e < NE && tb[e + 1] <= bi) ++e;
  if (e >= NE) return;
  const int t = bi - tb[e];
  const int start = offsets[e] + t * TS;
  const int n = min(TS, offsets[e + 1] - start);
  const int tid = threadIdx.x;

  if (tid < TS) {
    int bb = -1;
    if (tid < n) bb = perm[start + tid];
    rowB[tid] = bb;
  }
  __syncthreads();

  // stage gathered rows transposed: GT[k][row]
  #pragma unroll
  for (int it = 0; it < 4; ++it) {
    int idx = it * 512 + tid;            // 0..2047
    int k4 = idx >> 6, row = idx & 63;   // k4 0..31
    int bb = rowB[row];
    float4 x = make_float4(0.f, 0.f, 0.f, 0.f);
    if (bb >= 0) x = *(const float4*)(ld + (size_t)bb * (NQ * ND) + e * ND + (k4 << 2));
    GT[k4 * 4 + 0][row] = x.x;
    GT[k4 * 4 + 1][row] = x.y;
    GT[k4 * 4 + 2][row] = x.z;
    GT[k4 * 4 + 3][row] = x.w;
  }

  const float* W1e = W1 + (size_t)e * NCH * ND;
  const float* W2e = W2 + (size_t)e * ND * NCH;

  // ---- layer 1: H[64][256] = G @ W1^T ; 4x8 micro-tile (512 thr)
  const int cx = tid & 31, ry = tid >> 5;       // ry 0..15 -> rows ry*4..+4
  float acc[4][8];
  #pragma unroll
  for (int r = 0; r < 4; ++r)
    #pragma unroll
    for (int c = 0; c < 8; ++c) acc[r][c] = 0.f;

  for (int kc = 0; kc < 4; ++kc) {
    __syncthreads();
    {
      const int ch = tid & 255, hf = tid >> 8;  // hf 0/1
      const float* wrow = W1e + (size_t)ch * ND + kc * 32 + hf * 16;
      #pragma unroll
      for (int j4 = 0; j4 < 4; ++j4) {
        float4 x = *(const float4*)(wrow + (j4 << 2));
        Bc[hf * 16 + j4 * 4 + 0][ch] = x.x; Bc[hf * 16 + j4 * 4 + 1][ch] = x.y;
        Bc[hf * 16 + j4 * 4 + 2][ch] = x.z; Bc[hf * 16 + j4 * 4 + 3][ch] = x.w;
      }
    }
    __syncthreads();
    for (int kk = 0; kk < 32; ++kk) {
      int k = kc * 32 + kk;
      float a[4], bv[8];
      *(float4*)&a[0] = *(const float4*)&GT[k][ry * 4];
      *(float4*)&bv[0] = *(const float4*)&Bc[kk][cx * 8];
      *(float4*)&bv[4] = *(const float4*)&Bc[kk][cx * 8 + 4];
      #pragma unroll
      for (int r = 0; r < 4; ++r)
        #pragma unroll
        for (int c = 0; c < 8; ++c)
          acc[r][c] = fmaf(a[r], bv[c], acc[r][c]);
    }
  }

  float bias1[8];
  *(float4*)&bias1[0] = *(const float4*)(b1 + e * NCH + cx * 8);
  *(float4*)&bias1[4] = *(const float4*)(b1 + e * NCH + cx * 8 + 4);
  #pragma unroll
  for (int r = 0; r < 4; ++r) {
    float hv[8];
    #pragma unroll
    for (int c = 0; c < 8; ++c) {
      float x = acc[r][c] + bias1[c];
      hv[c] = 0.5f * x * (1.f + erff(x * 0.70710678118654752f));
    }
    *(float4*)&Hs[ry * 4 + r][cx * 8]     = *(float4*)&hv[0];
    *(float4*)&Hs[ry * 4 + r][cx * 8 + 4] = *(float4*)&hv[4];
  }

  // ---- layer 2: Out[64][128] = H @ W2^T ; 2x8 micro-tile (512 thr)
  const int cg = tid & 15, rg = tid >> 4;       // rg 0..31 -> rows rg*2..+2
  float acc2[2][8];
  #pragma unroll
  for (int r = 0; r < 2; ++r)
    #pragma unroll
    for (int c = 0; c < 8; ++c) acc2[r][c] = 0.f;

  for (int kc = 0; kc < 4; ++kc) {
    __syncthreads();                            // GT readers done / Hs ready / prev BT2 consumed
    #pragma unroll
    for (int it = 0; it < 4; ++it) {
      int idx = it * 512 + tid;                 // 0..2047
      int d = idx & 127, kk4 = idx >> 7;        // kk4 0..15
      float4 x = *(const float4*)(W2e + (size_t)d * NCH + kc * 64 + (kk4 << 2));
      BT2[kk4 * 4 + 0][d] = x.x; BT2[kk4 * 4 + 1][d] = x.y;
      BT2[kk4 * 4 + 2][d] = x.z; BT2[kk4 * 4 + 3][d] = x.w;
    }
    __syncthreads();
    for (int kk4 = 0; kk4 < 16; ++kk4) {
      int k = kc * 64 + kk4 * 4;
      float4 a0 = *(const float4*)&Hs[rg * 2 + 0][k];
      float4 a1 = *(const float4*)&Hs[rg * 2 + 1][k];
      #pragma unroll
      for (int j = 0; j < 4; ++j) {
        float bv[8];
        *(float4*)&bv[0] = *(const float4*)&BT2[kk4 * 4 + j][cg * 8];
        *(float4*)&bv[4] = *(const float4*)&BT2[kk4 * 4 + j][cg * 8 + 4];
        float aj0 = ((const float*)&a0)[j];
        float aj1 = ((const float*)&a1)[j];
        #pragma unroll
        for (int c = 0; c < 8; ++c) {
          acc2[0][c] = fmaf(aj0, bv[c], acc2[0][c]);
          acc2[1][c] = fmaf(aj1, bv[c], acc2[1][c]);
        }
      }
    }
  }

  float bias2[8];
  *(float4*)&bias2[0] = *(const float4*)(b2 + e * ND + cg * 8);
  *(float4*)&bias2[4] = *(const float4*)(b2 + e * ND + cg * 8 + 4);
  #pragma unroll
  for (int r = 0; r < 2; ++r) {
    int row = rg * 2 + r;
    int bb = rowB[row];
    if (bb < 0) continue;
    float ov[8];
    #pragma unroll
    for (int c = 0; c < 8; ++c) ov[c] = acc2[r][c] + bias2[c];
    *(float4*)(outv + (size_t)bb * ND + cg * 8)     = *(float4*)&ov[0];
    *(float4*)(outv + (size_t)bb * ND + cg * 8 + 4) = *(float4*)&ov[4];
  }
}

extern "C" void kernel_launch(void* const* d_in, const int* in_sizes, int n_in,
                              void* d_out, int out_size, void* d_ws, size_t ws_size,
                              hipStream_t stream) {
  const float* ld = (const float*)d_in[0];
  const float* sW = (const float*)d_in[1];
  const float* sb = (const float*)d_in[2];
  const float* W1 = (const float*)d_in[3];
  const float* b1 = (const float*)d_in[4];
  const float* W2 = (const float*)d_in[5];
  const float* b2 = (const float*)d_in[6];
  float* outv = (float*)d_out;                 // [B,128]
  float* logits = outv + (size_t)NB * ND;      // [B,15]

  int* counts  = (int*)d_ws;                             // [512], used at e*32
  int* cursor  = counts + 512;                           // [512], used at e*32
  int* offsets = counts + 1024;                          // [17]
  int* tb      = counts + 1056;                          // [17]
  unsigned char* eid = (unsigned char*)(counts + 1088);  // 65536 B
  int* perm = (int*)((char*)d_ws + 4352 + 65536);        // [B]

  k_init<<<1, 512, 0, stream>>>(counts);
  k_scene<<<NB / 4, 256, 0, stream>>>(ld, sW, sb, logits, eid);
  k_hist<<<NB / 1024, 256, 0, stream>>>(eid, counts);
  k_scan<<<1, 64, 0, stream>>>(counts, offsets, cursor, tb);
  k_scatter<<<NB / 256, 256, 0, stream>>>(eid, cursor, perm);
  k_mlp<<<NB / TS + NE, 512, 0, stream>>>(ld, W1, b1, W2, b2, offsets, tb, perm, outv);
}